// Round 1
// baseline (2461.388 us; speedup 1.0000x reference)
//
#include <hip/hip_runtime.h>

#define DEVI __device__ __forceinline__

typedef float  f32x4  __attribute__((ext_vector_type(4)));
typedef __bf16 bf16x8 __attribute__((ext_vector_type(8)));
typedef unsigned short u16x8 __attribute__((ext_vector_type(8)));

// ---------- helpers ----------
DEVI unsigned short f2bf(float f) {
    unsigned u = __builtin_bit_cast(unsigned, f);
    unsigned r = (u + 0x7fffu + ((u >> 16) & 1u)) >> 16;
    return (unsigned short)r;
}
DEVI float bf2f(unsigned short s) {
    return __builtin_bit_cast(float, (unsigned)s << 16);
}
DEVI u16x8 pack8(float4 a, float4 b) {
    u16x8 p;
    p[0] = f2bf(a.x); p[1] = f2bf(a.y); p[2] = f2bf(a.z); p[3] = f2bf(a.w);
    p[4] = f2bf(b.x); p[5] = f2bf(b.y); p[6] = f2bf(b.z); p[7] = f2bf(b.w);
    return p;
}
DEVI f32x4 mfma16(u16x8 a, u16x8 b, f32x4 c) {
    return __builtin_amdgcn_mfma_f32_16x16x32_bf16(
        __builtin_bit_cast(bf16x8, a), __builtin_bit_cast(bf16x8, b), c, 0, 0, 0);
}
DEVI float sigm(float x)   { return 1.f / (1.f + __expf(-x)); }
DEVI float tanh_f(float x) { return 1.f - 2.f / (1.f + __expf(2.f * x)); }

// dims
#define Hh 256
#define Bb 64
#define Tt 1024
#define MROWS (Bb * Tt)   // 65536

// ---------- K0: hp[b][k] = sum_h hidden[b][h] * W_w[k][h] (first H cols) ----------
__global__ __launch_bounds__(256) void hp_kernel(const float* __restrict__ hid,
                                                 const float* __restrict__ Ww,
                                                 float* __restrict__ hp) {
    int b = blockIdx.x, k = threadIdx.x;
    __shared__ __align__(16) float hs[Hh];
    hs[k] = hid[b * Hh + k];
    __syncthreads();
    const float4* w4 = (const float4*)(Ww + (size_t)k * 512);
    const float4* h4 = (const float4*)hs;
    float acc = 0.f;
#pragma unroll 8
    for (int i = 0; i < 64; i++) {
        float4 a = w4[i], x = h4[i];
        acc += a.x * x.x + a.y * x.y + a.z * x.z + a.w * x.w;
    }
    hp[b * Hh + k] = acc;
}

// ---------- GEMM: OUT = epilogue( A(65536x256) @ W^T )  BM=128 BN=64 K=256 ----------
// EPI 0: z = tanh(acc + hp[b][c] + W_b[c]) -> bf16 [r][c]
// EPI 1: scores = acc + V_b[c]            -> f32  [r][c]
// EPI 2: xproj  = acc + b_i[c]            -> bf16 [mat][t][b][c]
template <int EPI, bool ABF16>
__global__ __launch_bounds__(512) void gemm_k(
    const void* __restrict__ Aab,
    const float* __restrict__ W0, const float* __restrict__ W1, const float* __restrict__ W2,
    int wstride, int wcoloff,
    const float* __restrict__ bv0, const float* __restrict__ bv1, const float* __restrict__ bv2,
    const float* __restrict__ hp, const float* __restrict__ Wb,
    void* __restrict__ outv) {
    __shared__ __align__(16) unsigned short As[128 * 256];
    __shared__ __align__(16) unsigned short Bs[64 * 256];

    int tid = threadIdx.x;
    int bx = blockIdx.x, by = blockIdx.y;
    int mat = (EPI == 2) ? (by >> 2) : 0;
    int cb  = (EPI == 2) ? (by & 3) : by;
    int rowBase = bx * 128, colBase = cb * 64;
    const float* W  = (mat == 0) ? W0 : ((mat == 1) ? W1 : W2);
    const float* bv = (mat == 0) ? bv0 : ((mat == 1) ? bv1 : bv2);

    // stage A: 128 rows x 32 chunks(16B), swizzled g ^= (r&7)
    if (ABF16) {
        const unsigned short* A = (const unsigned short*)Aab;
#pragma unroll
        for (int i = 0; i < 8; i++) {
            int idx = i * 512 + tid, r = idx >> 5, g = idx & 31, gs = g ^ (r & 7);
            *(uint4*)&As[r * 256 + gs * 8] =
                *(const uint4*)(A + (((size_t)(rowBase + r)) << 8) + g * 8);
        }
    } else {
        const float* A = (const float*)Aab;
#pragma unroll
        for (int i = 0; i < 8; i++) {
            int idx = i * 512 + tid, r = idx >> 5, g = idx & 31, gs = g ^ (r & 7);
            const float* s = A + (((size_t)(rowBase + r)) << 8) + g * 8;
            float4 f0 = *(const float4*)s, f1 = *(const float4*)(s + 4);
            *(u16x8*)&As[r * 256 + gs * 8] = pack8(f0, f1);
        }
    }
    // stage B: 64 W-rows (output cols) x 32 chunks
#pragma unroll
    for (int i = 0; i < 4; i++) {
        int idx = i * 512 + tid, r = idx >> 5, g = idx & 31, gs = g ^ (r & 7);
        const float* s = W + (size_t)(colBase + r) * wstride + wcoloff + g * 8;
        float4 f0 = *(const float4*)s, f1 = *(const float4*)(s + 4);
        *(u16x8*)&Bs[r * 256 + gs * 8] = pack8(f0, f1);
    }
    __syncthreads();

    int wid = tid >> 6, lane = tid & 63, l15 = lane & 15, grp = lane >> 4;
    int wr = (wid >> 1) * 32, wc = (wid & 1) * 32;
    f32x4 acc[2][2] = {};
#pragma unroll
    for (int kc = 0; kc < 8; kc++) {
        u16x8 a[2], bb[2];
#pragma unroll
        for (int rt = 0; rt < 2; rt++) {
            int r = wr + rt * 16 + l15;
            int gs = (kc * 4 + grp) ^ (r & 7);
            a[rt] = *(const u16x8*)&As[r * 256 + gs * 8];
        }
#pragma unroll
        for (int ct = 0; ct < 2; ct++) {
            int r = wc + ct * 16 + l15;
            int gs = (kc * 4 + grp) ^ (r & 7);
            bb[ct] = *(const u16x8*)&Bs[r * 256 + gs * 8];
        }
#pragma unroll
        for (int rt = 0; rt < 2; rt++)
#pragma unroll
            for (int ct = 0; ct < 2; ct++)
                acc[rt][ct] = mfma16(a[rt], bb[ct], acc[rt][ct]);
    }
    // epilogue: D row = (lane>>4)*4 + i, col = lane&15
#pragma unroll
    for (int rt = 0; rt < 2; rt++)
#pragma unroll
        for (int ct = 0; ct < 2; ct++)
#pragma unroll
            for (int i = 0; i < 4; i++) {
                int rl = wr + rt * 16 + grp * 4 + i;
                int cl = wc + ct * 16 + l15;
                size_t r = (size_t)rowBase + rl;
                int c = colBase + cl;
                float v = acc[rt][ct][i];
                if (EPI == 0) {
                    v = tanh_f(v + hp[(r >> 10) * 256 + c] + Wb[c]);
                    ((unsigned short*)outv)[r * 256 + c] = f2bf(v);
                } else if (EPI == 1) {
                    ((float*)outv)[r * 256 + c] = v + bv[c];
                } else {
                    size_t t = r & 1023, b = r >> 10;
                    ((unsigned short*)outv)[(size_t)mat * 16777216 + (t * 64 + b) * 256 + c] =
                        f2bf(v + bv[c]);
                }
            }
}

// ---------- softmax over T, pass 1: per (b,k) online max/sumexp over a T-chunk ----------
__global__ __launch_bounds__(256) void softmax_pass1(const float* __restrict__ scores,
                                                     float* __restrict__ partMS) {
    int b = blockIdx.x, tc = blockIdx.y, k = threadIdx.x;
    const float* p = scores + ((size_t)b * Tt + tc * 128) * Hh + k;
    float m = -1e30f, S = 0.f;
    for (int i = 0; i < 128; i++) {
        float s = p[(size_t)i * Hh];
        float mn = fmaxf(m, s);
        S = S * __expf(m - mn) + __expf(s - mn);
        m = mn;
    }
    int idx = (b * 8 + tc) * Hh + k;
    partMS[idx * 2] = m;
    partMS[idx * 2 + 1] = S;
}

// ---------- softmax pass 2: combine partials, emit ctx (bf16) and x_attn ----------
__global__ __launch_bounds__(256) void softmax_pass2(const float* __restrict__ scores,
                                                     const float* __restrict__ partMS,
                                                     unsigned short* __restrict__ ctx,
                                                     float* __restrict__ x_attn) {
    int b = blockIdx.x, tc = blockIdx.y;
    int tid = threadIdx.x, w = tid >> 6, lane = tid & 63;
    float mj[4], Sj[4];
#pragma unroll
    for (int j = 0; j < 4; j++) {
        int k = lane + j * 64;
        float m = -1e30f;
#pragma unroll
        for (int c = 0; c < 8; c++)
            m = fmaxf(m, partMS[((b * 8 + c) * Hh + k) * 2]);
        float S = 0.f;
#pragma unroll
        for (int c = 0; c < 8; c++) {
            int idx = (b * 8 + c) * Hh + k;
            S += partMS[idx * 2 + 1] * __expf(partMS[idx * 2] - m);
        }
        mj[j] = m;
        Sj[j] = 1.f / S;
    }
    for (int i = 0; i < 32; i++) {
        int t = tc * 128 + w * 32 + i;
        const float* sp = scores + ((size_t)b * Tt + t) * Hh;
        unsigned short* cp = ctx + ((size_t)b * Tt + t) * Hh;
        float accsm = 0.f;
#pragma unroll
        for (int j = 0; j < 4; j++) {
            int k = lane + j * 64;
            float s = sp[k];
            float sm = __expf(s - mj[j]) * Sj[j];
            accsm += sm;
            cp[k] = f2bf(s * sm);
        }
#pragma unroll
        for (int o = 32; o >= 1; o >>= 1) accsm += __shfl_xor(accsm, o, 64);
        if (lane == 0) x_attn[b * Tt + t] = accsm;
    }
}

// ---------- GRU scan: one block per batch row, weights in registers ----------
__global__ __launch_bounds__(512) void scan_gru(
    const unsigned short* __restrict__ xg,
    const float* __restrict__ whr, const float* __restrict__ whz, const float* __restrict__ whn,
    const float* __restrict__ bhr, const float* __restrict__ bhz, const float* __restrict__ bhn,
    const float* __restrict__ hidden,
    float* __restrict__ outputs, float* __restrict__ hlast) {
    int b = blockIdx.x;
    int tid = threadIdx.x, w = tid >> 6, lane = tid & 63;
    int l15 = lane & 15, grp = lane >> 4;
    __shared__ __align__(16) unsigned short hb[Hh];

    // B-fragments for 3 matrices, 2 col-tiles (wave owns cols [32w, 32w+32)), 8 K-chunks
    u16x8 wf[3][2][8];
    const float* Ws[3] = {whr, whz, whn};
#pragma unroll
    for (int m = 0; m < 3; m++)
#pragma unroll
        for (int ct = 0; ct < 2; ct++) {
            int col = w * 32 + ct * 16 + l15;
#pragma unroll
            for (int kc = 0; kc < 8; kc++) {
                const float* s = Ws[m] + (size_t)col * Hh + kc * 32 + grp * 8;
                float4 f0 = *(const float4*)s, f1 = *(const float4*)(s + 4);
                wf[m][ct][kc] = pack8(f0, f1);
            }
        }

    int col0 = w * 32 + l15, col1 = col0 + 16;
    float bh0r = 0, bh0z = 0, bh0n = 0, bh1r = 0, bh1z = 0, bh1n = 0;
    float hp0 = 0.f, hp1 = 0.f;
    if (lane < 16) {
        bh0r = bhr[col0]; bh0z = bhz[col0]; bh0n = bhn[col0];
        bh1r = bhr[col1]; bh1z = bhz[col1]; bh1n = bhn[col1];
        hp0 = hidden[b * Hh + col0];
        hp1 = hidden[b * Hh + col1];
        hb[col0] = f2bf(hp0);
        hb[col1] = f2bf(hp1);
        // outputs[:,0,:] = h0 (exact f32)
        outputs[((size_t)b * Tt) * Hh + col0] = hp0;
        outputs[((size_t)b * Tt) * Hh + col1] = hp1;
    }
    const unsigned short* xr = xg;
    const unsigned short* xz = xg + 16777216;
    const unsigned short* xn = xg + 33554432;
    unsigned short nx0 = 0, nx1 = 0, nx2 = 0, nx3 = 0, nx4 = 0, nx5 = 0;
    if (lane < 16) {
        size_t off = ((size_t)1 * 64 + b) * Hh;
        nx0 = xr[off + col0]; nx1 = xr[off + col1];
        nx2 = xz[off + col0]; nx3 = xz[off + col1];
        nx4 = xn[off + col0]; nx5 = xn[off + col1];
    }
    __syncthreads();

    for (int t = 1; t < Tt; t++) {
        unsigned short cx0 = nx0, cx1 = nx1, cx2 = nx2, cx3 = nx3, cx4 = nx4, cx5 = nx5;
        int tnext = (t + 1 < Tt) ? t + 1 : t;
        if (lane < 16) {  // prefetch next step's x-projections (latency hidden by MFMA)
            size_t off = ((size_t)tnext * 64 + b) * Hh;
            nx0 = xr[off + col0]; nx1 = xr[off + col1];
            nx2 = xz[off + col0]; nx3 = xz[off + col1];
            nx4 = xn[off + col0]; nx5 = xn[off + col1];
        }
        f32x4 acc[3][2] = {};
#pragma unroll
        for (int kc = 0; kc < 8; kc++) {
            u16x8 af = *(const u16x8*)&hb[kc * 32 + grp * 8];  // broadcast read
#pragma unroll
            for (int m = 0; m < 3; m++)
#pragma unroll
                for (int ct = 0; ct < 2; ct++)
                    acc[m][ct] = mfma16(af, wf[m][ct][kc], acc[m][ct]);
        }
        float hn0 = 0.f, hn1 = 0.f;
        if (lane < 16) {
            float r0 = sigm(bf2f(cx0) + acc[0][0][0] + bh0r);
            float r1 = sigm(bf2f(cx1) + acc[0][1][0] + bh1r);
            float n0 = tanh_f(bf2f(cx4) + r0 * (acc[2][0][0] + bh0n));
            float n1 = tanh_f(bf2f(cx5) + r1 * (acc[2][1][0] + bh1n));
            float z0 = sigm(bf2f(cx2) + acc[1][0][0] + bh0z);
            float z1 = sigm(bf2f(cx3) + acc[1][1][0] + bh1z);
            hn0 = (1.f - z0) * n0 + z0 * hp0;
            hn1 = (1.f - z1) * n1 + z1 * hp1;
        }
        __syncthreads();  // all waves done reading hb
        if (lane < 16) {
            hb[col0] = f2bf(hn0);
            hb[col1] = f2bf(hn1);
            size_t ro = ((size_t)b * Tt + t) * Hh;
            outputs[ro + col0] = hn0;
            outputs[ro + col1] = hn1;
            hp0 = hn0;
            hp1 = hn1;
        }
        __syncthreads();  // new h visible
    }
    if (lane < 16) {
        hlast[b * Hh + col0] = hp0;
        hlast[b * Hh + col1] = hp1;
    }
}

// ---------- launch ----------
extern "C" void kernel_launch(void* const* d_in, const int* in_sizes, int n_in,
                              void* d_out, int out_size, void* d_ws, size_t ws_size,
                              hipStream_t stream) {
    const float* inputs = (const float*)d_in[0];
    const float* hidden = (const float*)d_in[1];
    const float* W_w  = (const float*)d_in[2];
    const float* W_b  = (const float*)d_in[3];
    const float* V_w  = (const float*)d_in[4];
    const float* V_b  = (const float*)d_in[5];
    const float* w_ir = (const float*)d_in[6];
    const float* w_iz = (const float*)d_in[7];
    const float* w_in = (const float*)d_in[8];
    const float* b_ir = (const float*)d_in[9];
    const float* b_iz = (const float*)d_in[10];
    const float* b_in = (const float*)d_in[11];
    const float* w_hr = (const float*)d_in[12];
    const float* w_hz = (const float*)d_in[13];
    const float* w_hn = (const float*)d_in[14];
    const float* b_hr = (const float*)d_in[15];
    const float* b_hz = (const float*)d_in[16];
    const float* b_hn = (const float*)d_in[17];

    // workspace layout (~135.5 MB)
    float* hp = (float*)d_ws;                                  // 65536 f32
    float* partMS = hp + 65536;                                // 64*8*256*2 f32
    unsigned short* zbuf = (unsigned short*)(partMS + 262144); // 16.7M bf16
    unsigned short* ctx = zbuf;                                // alias: z dead after GEMM2
    unsigned short* xgb = zbuf + 16777216;                     // 3 x 16.7M bf16

    float* scores  = (float*)d_out;         // scores staged in outputs slot (dead before scan)
    float* outputs = (float*)d_out;
    float* hlast   = outputs + 16777216;
    float* x_attn  = hlast + 16384;

    hp_kernel<<<64, 256, 0, stream>>>(hidden, W_w, hp);

    gemm_k<0, false><<<dim3(512, 4), 512, 0, stream>>>(
        inputs, W_w, nullptr, nullptr, 512, 256,
        nullptr, nullptr, nullptr, hp, W_b, zbuf);

    gemm_k<1, true><<<dim3(512, 4), 512, 0, stream>>>(
        zbuf, V_w, nullptr, nullptr, 256, 0,
        V_b, nullptr, nullptr, nullptr, nullptr, scores);

    softmax_pass1<<<dim3(64, 8), 256, 0, stream>>>(scores, partMS);
    softmax_pass2<<<dim3(64, 8), 256, 0, stream>>>(scores, partMS, ctx, x_attn);

    gemm_k<2, true><<<dim3(512, 12), 512, 0, stream>>>(
        ctx, w_ir, w_iz, w_in, 256, 0,
        b_ir, b_iz, b_in, nullptr, nullptr, xgb);

    scan_gru<<<64, 512, 0, stream>>>(
        xgb, w_hr, w_hz, w_hn, b_hr, b_hz, b_hn, hidden, outputs, hlast);
}